// Round 9
// baseline (166.610 us; speedup 1.0000x reference)
//
#include <hip/hip_runtime.h>

#define NPTS   8192
#define NB     256          // one block per CU (128KB LDS => 1 block/CU)
#define NT     512          // 8 waves = 2 waves/SIMD (TLP hides latency)
#define NG8    16           // 16 global groups of 8 dst-steps (512 dsts each)
#define HGRP   8            // groups per wave (half the dst range)
// NOTE R5/R6: register-caching dst groups -> spill disaster / slower. No dreg.
// NOTE R8: splitting SRCS across 8 waves doubled LDS reads (each wave sweeps
// all dsts) -> port-bound regression. This version splits the DST RANGE:
// pair p=wav>>1 owns 8 srcs; wave h=wav&1 sweeps half the dsts; halves merge
// via LDS. Total LDS reads/CU/iter = 512 (same as the best 4-wave version).
#define MAXIT  20
#define TOLER  1e-3
#define SPINCAP 200000000u

typedef unsigned long long u64;
typedef unsigned int u32;
typedef float f2 __attribute__((ext_vector_type(2)));   // -> v_pk_fma_f32
typedef double dbl2 __attribute__((ext_vector_type(2))); // 16B LDS store

// ---- ws byte-offset layout (~67 KB) ----
#define WS_PART    0        // double[2][16][NB] transposed partials, 65536 B
#define WS_FLAGS   65536    // int[NB] generation flags, 1024 B
// Harness poisons ws to 0xAA; 0xAAAAAAAA as signed int is NEGATIVE and all
// generation values are in [1,22], so poisoned flags never satisfy >= gen.

__device__ inline double atom_ld(const double* p) {
  return __hip_atomic_load(p, __ATOMIC_RELAXED, __HIP_MEMORY_SCOPE_AGENT);
}
__device__ inline void atom_st(double* p, double v) {
  __hip_atomic_store(p, v, __ATOMIC_RELAXED, __HIP_MEMORY_SCOPE_AGENT);
}
__device__ inline int atom_ldi(const int* p) {
  return __hip_atomic_load(p, __ATOMIC_RELAXED, __HIP_MEMORY_SCOPE_AGENT);
}
__device__ inline void atom_sti(int* p, int v) {
  __hip_atomic_store(p, v, __ATOMIC_RELAXED, __HIP_MEMORY_SCOPE_AGENT);
}

// Analytic symmetric 3x3 eigendecomposition (fp32), eigenvalues DESCENDING.
__device__ void eig3f(const float K[3][3], float w[3], float V[3][3])
{
  const float p1 = K[0][1]*K[0][1] + K[0][2]*K[0][2] + K[1][2]*K[1][2];
  const float q  = (K[0][0] + K[1][1] + K[2][2]) * (1.f/3.f);
  const float p2 = (K[0][0]-q)*(K[0][0]-q) + (K[1][1]-q)*(K[1][1]-q)
                 + (K[2][2]-q)*(K[2][2]-q) + 2.f*p1;
  if (p2 < 1e-20f) {
    w[0]=w[1]=w[2]=q;
    V[0][0]=1;V[1][0]=0;V[2][0]=0; V[0][1]=0;V[1][1]=1;V[2][1]=0;
    V[0][2]=0;V[1][2]=0;V[2][2]=1;
    return;
  }
  const float p = sqrtf(p2 * (1.f/6.f));
  const float ip = 1.f / p;
  float Bm[3][3];
  for (int i = 0; i < 3; ++i)
    for (int j = 0; j < 3; ++j)
      Bm[i][j] = (K[i][j] - ((i==j) ? q : 0.f)) * ip;
  float detB = Bm[0][0]*(Bm[1][1]*Bm[2][2] - Bm[1][2]*Bm[2][1])
             - Bm[0][1]*(Bm[1][0]*Bm[2][2] - Bm[1][2]*Bm[2][0])
             + Bm[0][2]*(Bm[1][0]*Bm[2][1] - Bm[1][1]*Bm[2][0]);
  float r = fminf(1.f, fmaxf(-1.f, detB * 0.5f));
  const float phi = acosf(r) * (1.f/3.f);
  w[0] = q + 2.f*p*cosf(phi);
  w[2] = q + 2.f*p*cosf(phi + 2.0943951023931953f);
  w[1] = 3.f*q - w[0] - w[2];
  for (int kk = 0; kk < 2; ++kk) {
    const int k = (kk == 0) ? 0 : 2;
    float lam = w[k];
    float r0[3] = {K[0][0]-lam, K[0][1], K[0][2]};
    float r1[3] = {K[1][0], K[1][1]-lam, K[1][2]};
    float r2[3] = {K[2][0], K[2][1], K[2][2]-lam};
    float c01[3] = {r0[1]*r1[2]-r0[2]*r1[1], r0[2]*r1[0]-r0[0]*r1[2], r0[0]*r1[1]-r0[1]*r1[0]};
    float c12[3] = {r1[1]*r2[2]-r1[2]*r2[1], r1[2]*r2[0]-r1[0]*r2[2], r1[0]*r2[1]-r1[1]*r2[0]};
    float c20[3] = {r2[1]*r0[2]-r2[2]*r0[1], r2[2]*r0[0]-r2[0]*r0[2], r2[0]*r0[1]-r2[1]*r0[0]};
    float n01 = c01[0]*c01[0]+c01[1]*c01[1]+c01[2]*c01[2];
    float n12 = c12[0]*c12[0]+c12[1]*c12[1]+c12[2]*c12[2];
    float n20 = c20[0]*c20[0]+c20[1]*c20[1]+c20[2]*c20[2];
    float* best = c01; float nb = n01;
    if (n12 > nb) { best = c12; nb = n12; }
    if (n20 > nb) { best = c20; nb = n20; }
    float inv = 1.f / sqrtf(nb + 1e-30f);
    V[0][k]=best[0]*inv; V[1][k]=best[1]*inv; V[2][k]=best[2]*inv;
  }
  V[0][1] = V[1][2]*V[2][0] - V[2][2]*V[1][0];
  V[1][1] = V[2][2]*V[0][0] - V[0][2]*V[2][0];
  V[2][1] = V[0][2]*V[1][0] - V[1][2]*V[0][0];
  float nm = sqrtf(V[0][1]*V[0][1]+V[1][1]*V[1][1]+V[2][1]*V[2][1]) + 1e-30f;
  V[0][1] /= nm; V[1][1] /= nm; V[2][1] /= nm;
}

// Kabsch (fp32): R = V'U^T with last V column flipped if det<0.
__device__ void kabsch_Rf(const float H[3][3], float R[3][3])
{
  float K[3][3];
  for (int i = 0; i < 3; ++i)
    for (int j = 0; j < 3; ++j) {
      float s = 0.f;
      for (int k = 0; k < 3; ++k) s += H[k][i] * H[k][j];
      K[i][j] = s;
    }
  float w[3], V[3][3];
  eig3f(K, w, V);
  float U[3][3];
  for (int k = 0; k < 3; ++k) {
    float u0 = H[0][0]*V[0][k] + H[0][1]*V[1][k] + H[0][2]*V[2][k];
    float u1 = H[1][0]*V[0][k] + H[1][1]*V[1][k] + H[1][2]*V[2][k];
    float u2 = H[2][0]*V[0][k] + H[2][1]*V[1][k] + H[2][2]*V[2][k];
    float n = sqrtf(u0*u0 + u1*u1 + u2*u2);
    if (n > 1e-18f) { u0 /= n; u1 /= n; u2 /= n; }
    else if (k == 2) {
      u0 = U[1][0]*U[2][1] - U[2][0]*U[1][1];
      u1 = U[2][0]*U[0][1] - U[0][0]*U[2][1];
      u2 = U[0][0]*U[1][1] - U[1][0]*U[0][1];
      float n2 = sqrtf(u0*u0 + u1*u1 + u2*u2) + 1e-30f;
      u0 /= n2; u1 /= n2; u2 /= n2;
    } else {
      u0 = (k == 0) ? 1.f : 0.f; u1 = (k == 1) ? 1.f : 0.f; u2 = 0.f;
    }
    U[0][k] = u0; U[1][k] = u1; U[2][k] = u2;
  }
  float R0[3][3];
  for (int i = 0; i < 3; ++i)
    for (int j = 0; j < 3; ++j)
      R0[i][j] = V[i][0]*U[j][0] + V[i][1]*U[j][1] + V[i][2]*U[j][2];
  float det = R0[0][0]*(R0[1][1]*R0[2][2] - R0[1][2]*R0[2][1])
            - R0[0][1]*(R0[1][0]*R0[2][2] - R0[1][2]*R0[2][0])
            + R0[0][2]*(R0[1][0]*R0[2][1] - R0[1][1]*R0[2][0]);
  if (det < 0.f)
    for (int i = 0; i < 3; ++i)
      for (int j = 0; j < 3; ++j)
        R0[i][j] -= 2.f * V[i][2] * U[j][2];
  for (int i = 0; i < 3; ++i)
    for (int j = 0; j < 3; ++j)
      R[i][j] = R0[i][j];
}

// Generation-flag grid barrier with s_sleep backoff.
__device__ inline void flag_barrier(int* flags, int blk, int gen,
                                    int tid, int wav, int lane)
{
  __syncthreads();
  if (tid == 0) {
    __threadfence();          // release partials at agent scope
    atom_sti(&flags[blk], gen);
  }
  if (wav == 0) {
    const int base = lane * 4;
    u32 spins = 0;
    bool ok = false;
    while (!ok && spins < SPINCAP) {
      int f0 = atom_ldi(&flags[base + 0]);
      int f1 = atom_ldi(&flags[base + 1]);
      int f2_ = atom_ldi(&flags[base + 2]);
      int f3 = atom_ldi(&flags[base + 3]);
      ok = __all((f0 >= gen) && (f1 >= gen) && (f2_ >= gen) && (f3 >= gen));
      if (!ok) __builtin_amdgcn_s_sleep(2); // ~128 cyc backoff
      ++spins;
    }
  }
  __syncthreads();
  __threadfence();            // acquire everyone's partials
}

// Persistent kernel: Bp staged into LDS ONCE; all 20 iterations + final
// best-fit. block b owns src points b*32..b*32+31. Pair p = wav>>1 owns 8
// srcs (in registers, both waves of the pair); wave h = wav&1 sweeps dst
// half h. Every block redundantly reduces+solves (deterministic).
__global__ __launch_bounds__(NT, 1)
void icp_all(const float* __restrict__ A, const float* __restrict__ B,
             char* __restrict__ ws, float* __restrict__ out)
{
  double* partials = (double*)(ws + WS_PART); // [2][16][NB]
  int*    flags    = (int*)(ws + WS_FLAGS);

  __shared__ __align__(16) float4 bp_lds[NPTS];   // 128 KB, persistent
  __shared__ __align__(16) double red1[32 * 16];  // per-src rows
  __shared__ double red2[8 * 16];                 // wave sums / S[k]
  __shared__ float  mE[8][8];                     // per-wave half-argmin e
  __shared__ int    mM[8][8];                     // per-wave half-argmin meta
  __shared__ float  Tl[12];
  __shared__ int    dl;

  const int tid  = threadIdx.x;
  const int blk  = blockIdx.x;
  const int wav  = tid >> 6;   // 0..7
  const int lane = tid & 63;
  const int pr   = wav >> 1;   // pair 0..3 (owns 8 srcs)
  const int hh   = wav & 1;    // dst half 0/1
  const int qbase = blk * 32 + pr * 8;
  const int dbase = hh * (HGRP * 512); // first dst of this wave's half

  // ---- stage Bp once (B is constant across all iterations) ----
  for (int i = tid; i < NPTS; i += NT) {
    float bx = B[3*i], by = B[3*i+1], bz = B[3*i+2];
    bp_lds[i] = make_float4(2.f*bx, 2.f*by, 2.f*bz, bx*bx + by*by + bz*bz);
  }

  float ax[8], ay[8], az[8], sx[8], sy[8], sz[8];
  #pragma unroll
  for (int i = 0; i < 8; ++i) { // broadcast loads: all lanes hold all 8 src
    int p = qbase + i;
    ax[i] = A[3*p]; ay[i] = A[3*p+1]; az[i] = A[3*p+2];
    sx[i] = ax[i];  sy[i] = ay[i];    sz[i] = az[i];
  }
  __syncthreads(); // bp_lds ready

  double prev_err = 0.0; // tid0-meaningful; identical on every block
  int it = 0;
  for (; it < MAXIT; ++it) {
    const int par = it & 1;
    // ---- 1-NN half-sweep: 8 groups of 8 dsts, packed math, deferred idx ----
    f2 nsx2[4], nsy2[4], nsz2[4];
    #pragma unroll
    for (int k = 0; k < 4; ++k) {
      f2 vx = { -sx[2*k], -sx[2*k+1] };
      f2 vy = { -sy[2*k], -sy[2*k+1] };
      f2 vz = { -sz[2*k], -sz[2*k+1] };
      nsx2[k] = vx; nsy2[k] = vy; nsz2[k] = vz;
    }

    float emin[8]; int gmin[8];
    #pragma unroll
    for (int i = 0; i < 8; ++i) { emin[i] = 3.4e38f; gmin[i] = 0; }

    float4 dd[8];
    #pragma unroll
    for (int m = 0; m < 8; ++m) dd[m] = bp_lds[dbase + m * 64 + lane];

    for (int g = 0; g < HGRP - 1; ++g) {
      f2 run[4];
      #pragma unroll
      for (int m = 0; m < 8; ++m) {
        f2 dx2 = { dd[m].x, dd[m].x };
        f2 dy2 = { dd[m].y, dd[m].y };
        f2 dz2 = { dd[m].z, dd[m].z };
        f2 dw2 = { dd[m].w, dd[m].w };
        #pragma unroll
        for (int k = 0; k < 4; ++k) {
          // e = |b|^2 - 2 s.b ; argmin_j e == argmin_j d2
          f2 e2 = __builtin_elementwise_fma(nsx2[k], dx2,
                   __builtin_elementwise_fma(nsy2[k], dy2,
                    __builtin_elementwise_fma(nsz2[k], dz2, dw2)));
          run[k] = (m == 0) ? e2 : __builtin_elementwise_min(run[k], e2);
        }
        dd[m] = bp_lds[dbase + (g + 1) * 512 + m * 64 + lane]; // refill
      }
      #pragma unroll
      for (int k = 0; k < 4; ++k) {
        if (run[k].x < emin[2*k])   gmin[2*k]   = g;
        emin[2*k]   = fminf(emin[2*k],   run[k].x);
        if (run[k].y < emin[2*k+1]) gmin[2*k+1] = g;
        emin[2*k+1] = fminf(emin[2*k+1], run[k].y);
      }
    }
    { // epilogue group g = HGRP-1, no refill
      const int g = HGRP - 1;
      f2 run[4];
      #pragma unroll
      for (int m = 0; m < 8; ++m) {
        f2 dx2 = { dd[m].x, dd[m].x };
        f2 dy2 = { dd[m].y, dd[m].y };
        f2 dz2 = { dd[m].z, dd[m].z };
        f2 dw2 = { dd[m].w, dd[m].w };
        #pragma unroll
        for (int k = 0; k < 4; ++k) {
          f2 e2 = __builtin_elementwise_fma(nsx2[k], dx2,
                   __builtin_elementwise_fma(nsy2[k], dy2,
                    __builtin_elementwise_fma(nsz2[k], dz2, dw2)));
          run[k] = (m == 0) ? e2 : __builtin_elementwise_min(run[k], e2);
        }
      }
      #pragma unroll
      for (int k = 0; k < 4; ++k) {
        if (run[k].x < emin[2*k])   gmin[2*k]   = g;
        emin[2*k]   = fminf(emin[2*k],   run[k].x);
        if (run[k].y < emin[2*k+1]) gmin[2*k+1] = g;
        emin[2*k+1] = fminf(emin[2*k+1], run[k].y);
      }
    }

    // meta carries GLOBAL group id: ((hh*HGRP + g)<<6)|lane. Lexicographic
    // (e, meta) min == strict-< first-group argmin globally (lower meta =
    // lower j region; same tie rule as prior rounds).
    int meta[8];
    #pragma unroll
    for (int i = 0; i < 8; ++i) meta[i] = ((hh * HGRP + gmin[i]) << 6) | lane;
    #pragma unroll
    for (int m = 1; m < 64; m <<= 1) {
      #pragma unroll
      for (int i = 0; i < 8; ++i) {
        float eo = __shfl_xor(emin[i], m, 64);
        int   mo = __shfl_xor(meta[i], m, 64);
        if (eo < emin[i] || (eo == emin[i] && mo < meta[i])) { emin[i] = eo; meta[i] = mo; }
      }
    }

    // ---- publish per-wave half results (lane k writes slot k, static sel) --
    if (lane < 8) {
      float se = emin[0]; int sm = meta[0];
      #pragma unroll
      for (int k = 1; k < 8; ++k) {
        const bool p = (lane == k);
        se = p ? emin[k] : se;  sm = p ? meta[k] : sm;
      }
      mE[wav][lane] = se;  mM[wav][lane] = sm;
    }
    __syncthreads();

    // ---- even wave of each pair: merge halves, resolve, write red1 ----
    if (hh == 0) {
      #pragma unroll
      for (int i = 0; i < 8; ++i) {
        float eo = mE[wav + 1][i]; int mo = mM[wav + 1][i];
        if (eo < emin[i] || (eo == emin[i] && mo < meta[i])) { emin[i] = eo; meta[i] = mo; }
      }
      // lane handles src isrc = lane>>3, slots (lane&7)*2, +1  (R4 scheme)
      const int isrc = lane >> 3;
      float em = emin[0]; int mt = meta[0];
      float sxi = sx[0], syi = sy[0], szi = sz[0];
      #pragma unroll
      for (int k = 1; k < 8; ++k) {
        const bool p = (isrc == k);
        em  = p ? emin[k] : em;   mt  = p ? meta[k] : mt;
        sxi = p ? sx[k]  : sxi;   syi = p ? sy[k]  : syi;   szi = p ? sz[k] : szi;
      }
      const int gg = mt >> 6, ll = mt & 63;
      const int j0 = gg * 512 + ll;
      int jj = j0;
      #pragma unroll
      for (int m = 7; m >= 0; --m) { // descending: last assign = FIRST member
        float4 c = bp_lds[j0 + m * 64];
        float e = fmaf(-sxi, c.x, fmaf(-syi, c.y, fmaf(-szi, c.z, c.w)));
        jj = (e == em) ? (j0 + m * 64) : jj;
      }
      float4 dmt = bp_lds[jj];
      const float bxm = 0.5f*dmt.x, bym = 0.5f*dmt.y, bzm = 0.5f*dmt.z; // exact
      const double dsx = (double)sxi, dsy = (double)syi, dsz = (double)szi;
      const double dbx = (double)bxm, dby = (double)bym, dbz = (double)bzm;
      double w0, w1;
      switch (lane & 7) {
        case 0: w0 = dsx;       w1 = dsy;       break;
        case 1: w0 = dsz;       w1 = dbx;       break;
        case 2: w0 = dby;       w1 = dbz;       break;
        case 3: w0 = dsx * dbx; w1 = dsx * dby; break;
        case 4: w0 = dsx * dbz; w1 = dsy * dbx; break;
        case 5: w0 = dsy * dby; w1 = dsy * dbz; break;
        case 6: w0 = dsz * dbx; w1 = dsz * dby; break;
        default: {
          const float s2 = sxi*sxi + syi*syi + szi*szi;
          const float d2f = em + s2;
          w0 = dsz * dbz;
          w1 = (double)sqrtf(fmaxf(d2f, 0.f) + 1e-12f);
        } break;
      }
      dbl2 wv = { w0, w1 };
      *(dbl2*)&red1[(pr * 8 + isrc) * 16 + (lane & 7) * 2] = wv;
    }
    __syncthreads();

    // ---- per-wave reduction: wave w reduces rows w*4..w*4+3 ----
    {
      const int k16 = lane & 15, h2 = lane >> 4; // h2 = 0..3
      double s = red1[(wav*4 + h2)*16 + k16];
      s += __shfl_xor(s, 16, 64);
      s += __shfl_xor(s, 32, 64);
      if (lane < 16) red2[wav * 16 + k16] = s;
    }
    __syncthreads();
    if (tid < 16) { // transposed store: partials[par][k=tid][blk]
      double ssum = red2[tid] + red2[16+tid] + red2[32+tid] + red2[48+tid]
                  + red2[64+tid] + red2[80+tid] + red2[96+tid] + red2[112+tid];
      atom_st(&partials[((size_t)par * 16 + tid) * NB + blk], ssum);
    }
    flag_barrier(flags, blk, it + 1, tid, wav, lane);

    // ---- every block: reduce 256 partials, SPLIT-K: wave w owns rows 2w,2w+1
    {
      double s0, s1;
      #pragma unroll
      for (int j = 0; j < 2; ++j) {
        const int k = wav * 2 + j;
        const double* row = &partials[((size_t)par * 16 + k) * NB + lane * 4];
        double t0 = atom_ld(row + 0), t1 = atom_ld(row + 1);
        double t2 = atom_ld(row + 2), t3 = atom_ld(row + 3);
        double s = ((t0 + t1) + (t2 + t3));
        #pragma unroll
        for (int m = 1; m < 64; m <<= 1) s += __shfl_xor(s, m, 64);
        if (j == 0) s0 = s; else s1 = s;
      }
      if (lane == 0) { red2[wav*2 + 0] = s0; red2[wav*2 + 1] = s1; }
    }
    __syncthreads();
    if (tid == 0) {
      double S[16];
      for (int k = 0; k < 16; ++k) S[k] = red2[k];
      const double invN = 1.0 / NPTS;
      double cAv[3] = {S[0]*invN, S[1]*invN, S[2]*invN};
      double cBv[3] = {S[3]*invN, S[4]*invN, S[5]*invN};
      float H[3][3];
      for (int i = 0; i < 3; ++i)
        for (int j = 0; j < 3; ++j)
          H[i][j] = (float)(S[6 + i*3 + j] - (double)NPTS * cAv[i] * cBv[j]);
      double err = S[15] * invN;           // convergence stays fp64
      int conv = (fabs(prev_err - err) < TOLER) ? 1 : 0;
      prev_err = err;
      float R[3][3];
      kabsch_Rf(H, R);                     // rotation solve in fp32
      float t0 = (float)cBv[0] - (R[0][0]*(float)cAv[0] + R[0][1]*(float)cAv[1] + R[0][2]*(float)cAv[2]);
      float t1 = (float)cBv[1] - (R[1][0]*(float)cAv[0] + R[1][1]*(float)cAv[1] + R[1][2]*(float)cAv[2]);
      float t2 = (float)cBv[2] - (R[2][0]*(float)cAv[0] + R[2][1]*(float)cAv[1] + R[2][2]*(float)cAv[2]);
      Tl[0]=R[0][0]; Tl[1]=R[0][1]; Tl[2]=R[0][2];
      Tl[3]=R[1][0]; Tl[4]=R[1][1]; Tl[5]=R[1][2];
      Tl[6]=R[2][0]; Tl[7]=R[2][1]; Tl[8]=R[2][2];
      Tl[9]=t0; Tl[10]=t1; Tl[11]=t2;
      dl = conv;
    }
    __syncthreads();
    { // apply T in fp32 (both waves of a pair update identically)
      float r00=Tl[0],r01=Tl[1],r02=Tl[2],r10=Tl[3],r11=Tl[4],r12=Tl[5];
      float r20=Tl[6],r21=Tl[7],r22=Tl[8],t0=Tl[9],t1=Tl[10],t2=Tl[11];
      int done = dl;
      #pragma unroll
      for (int i = 0; i < 8; ++i) {
        float nx = r00*sx[i] + r01*sy[i] + r02*sz[i] + t0;
        float ny = r10*sx[i] + r11*sy[i] + r12*sz[i] + t1;
        float nz = r20*sx[i] + r21*sy[i] + r22*sz[i] + t2;
        sx[i]=nx; sy[i]=ny; sz[i]=nz;
      }
      if (done) break; // uniform decision across all blocks
    }
  }

  // ---- final best_fit_transform(A, src): H = sum a (x) s - N cA cS^T ----
  const int fpar = (it < MAXIT) ? ((it + 1) & 1) : (MAXIT & 1);
  const int fgen = (it < MAXIT) ? (it + 2) : (MAXIT + 1);
  if (hh == 0) { // even wave writes its pair's 8 rows (a, s, a x s, 0)
    const int isrc = lane >> 3;
    float axi = ax[0], ayi = ay[0], azi = az[0];
    float sxi = sx[0], syi = sy[0], szi = sz[0];
    #pragma unroll
    for (int k = 1; k < 8; ++k) {
      const bool p = (isrc == k);
      axi = p ? ax[k] : axi;  ayi = p ? ay[k] : ayi;  azi = p ? az[k] : azi;
      sxi = p ? sx[k] : sxi;  syi = p ? sy[k] : syi;  szi = p ? sz[k] : szi;
    }
    const double dax = (double)axi, day = (double)ayi, daz = (double)azi;
    const double dsx = (double)sxi, dsy = (double)syi, dsz = (double)szi;
    double w0, w1;
    switch (lane & 7) {
      case 0: w0 = dax;       w1 = day;       break;
      case 1: w0 = daz;       w1 = dsx;       break;
      case 2: w0 = dsy;       w1 = dsz;       break;
      case 3: w0 = dax * dsx; w1 = dax * dsy; break;
      case 4: w0 = dax * dsz; w1 = day * dsx; break;
      case 5: w0 = day * dsy; w1 = day * dsz; break;
      case 6: w0 = daz * dsx; w1 = daz * dsy; break;
      default: w0 = daz * dsz; w1 = 0.0;      break;
    }
    dbl2 wv = { w0, w1 };
    *(dbl2*)&red1[(pr * 8 + isrc) * 16 + (lane & 7) * 2] = wv;
  }
  __syncthreads();
  { // per-wave reduction: wave w reduces rows w*4..w*4+3
    const int k16 = lane & 15, h2 = lane >> 4;
    double s = red1[(wav*4 + h2)*16 + k16];
    s += __shfl_xor(s, 16, 64);
    s += __shfl_xor(s, 32, 64);
    if (lane < 16) red2[wav * 16 + k16] = s;
  }
  __syncthreads();
  if (tid < 16) {
    double ssum = red2[tid] + red2[16+tid] + red2[32+tid] + red2[48+tid]
                + red2[64+tid] + red2[80+tid] + red2[96+tid] + red2[112+tid];
    atom_st(&partials[((size_t)fpar * 16 + tid) * NB + blk], ssum);
  }
  if (blk != 0) { // non-output blocks: just arrive (release) and exit
    __syncthreads();
    if (tid == 0) { __threadfence(); atom_sti(&flags[blk], fgen); }
    return;
  }
  flag_barrier(flags, blk, fgen, tid, wav, lane);

  { // block0: split-k reduce + solve + write out
    double s0, s1;
    #pragma unroll
    for (int j = 0; j < 2; ++j) {
      const int k = wav * 2 + j;
      const double* row = &partials[((size_t)fpar * 16 + k) * NB + lane * 4];
      double t0 = atom_ld(row + 0), t1 = atom_ld(row + 1);
      double t2 = atom_ld(row + 2), t3 = atom_ld(row + 3);
      double s = ((t0 + t1) + (t2 + t3));
      #pragma unroll
      for (int m = 1; m < 64; m <<= 1) s += __shfl_xor(s, m, 64);
      if (j == 0) s0 = s; else s1 = s;
    }
    if (lane == 0) { red2[wav*2 + 0] = s0; red2[wav*2 + 1] = s1; }
  }
  __syncthreads();
  if (tid == 0) {
    double S[16];
    for (int k = 0; k < 16; ++k) S[k] = red2[k];
    const double invN = 1.0 / NPTS;
    double cAv[3] = {S[0]*invN, S[1]*invN, S[2]*invN};
    double cSv[3] = {S[3]*invN, S[4]*invN, S[5]*invN};
    float H[3][3];
    for (int i = 0; i < 3; ++i)
      for (int j = 0; j < 3; ++j)
        H[i][j] = (float)(S[6 + i*3 + j] - (double)NPTS * cAv[i] * cSv[j]);
    float R[3][3];
    kabsch_Rf(H, R);
    float u0 = (float)cSv[0] - (R[0][0]*(float)cAv[0] + R[0][1]*(float)cAv[1] + R[0][2]*(float)cAv[2]);
    float u1 = (float)cSv[1] - (R[1][0]*(float)cAv[0] + R[1][1]*(float)cAv[1] + R[1][2]*(float)cAv[2]);
    float u2 = (float)cSv[2] - (R[2][0]*(float)cAv[0] + R[2][1]*(float)cAv[1] + R[2][2]*(float)cAv[2]);
    out[0]=R[0][0]; out[1]=R[0][1]; out[2]=R[0][2]; out[3]=u0;
    out[4]=R[1][0]; out[5]=R[1][1]; out[6]=R[1][2]; out[7]=u1;
    out[8]=R[2][0]; out[9]=R[2][1]; out[10]=R[2][2]; out[11]=u2;
    out[12]=0.f; out[13]=0.f; out[14]=0.f; out[15]=1.f;
  }
}

extern "C" void kernel_launch(void* const* d_in, const int* in_sizes, int n_in,
                              void* d_out, int out_size, void* d_ws, size_t ws_size,
                              hipStream_t stream) {
  const float* A = (const float*)d_in[0];
  const float* B = (const float*)d_in[1];
  float* out = (float*)d_out;
  char* ws = (char*)d_ws; // needs ~67 KB

  hipLaunchKernelGGL(icp_all, dim3(NB), dim3(NT), 0, stream, A, B, ws, out);
}

// Round 10
// 140.514 us; speedup vs baseline: 1.1857x; 1.1857x over previous
//
#include <hip/hip_runtime.h>

#define NPTS   8192
#define NB     256          // one block per CU (128KB LDS => 1 block/CU)
#define NT     256          // 4 waves; each wave owns 8 src points
#define SRCW   8
#define NG8    16           // 16 groups of 8 dst-steps (8*64 dsts per group)
// LESSONS (do not retry):
// R5/R6: register-caching dst groups -> spill disaster / slower (VALU-bound).
// R8: NT=512 split-SRCS doubled LDS reads -> port-bound, +18us.
// R9: NT=512 split-DSTS kept traffic flat but coordination (butterflies,
//     publish/merge, 8-wave barrier skew) cost +65us dispatch. 4 waves is
//     structurally optimal for this kernel.
#define MAXIT  20
#define TOLER  1e-3
#define SPINCAP 200000000u

typedef unsigned long long u64;
typedef unsigned int u32;
typedef float f2 __attribute__((ext_vector_type(2)));   // -> v_pk_fma_f32
typedef double dbl2 __attribute__((ext_vector_type(2))); // 16B LDS store

// ---- ws byte-offset layout (~67 KB) ----
#define WS_PART    0        // double[2][16][NB] transposed partials, 65536 B
#define WS_FLAGS   65536    // int[NB] generation flags, 1024 B
// Harness poisons ws to 0xAA; 0xAAAAAAAA as signed int is NEGATIVE and all
// generation values are in [1,22], so poisoned flags never satisfy >= gen.

__device__ inline double atom_ld(const double* p) {
  return __hip_atomic_load(p, __ATOMIC_RELAXED, __HIP_MEMORY_SCOPE_AGENT);
}
__device__ inline void atom_st(double* p, double v) {
  __hip_atomic_store(p, v, __ATOMIC_RELAXED, __HIP_MEMORY_SCOPE_AGENT);
}
__device__ inline int atom_ldi(const int* p) {
  return __hip_atomic_load(p, __ATOMIC_RELAXED, __HIP_MEMORY_SCOPE_AGENT);
}
__device__ inline void atom_sti(int* p, int v) {
  __hip_atomic_store(p, v, __ATOMIC_RELAXED, __HIP_MEMORY_SCOPE_AGENT);
}

// Analytic symmetric 3x3 eigendecomposition (fp32), eigenvalues DESCENDING.
__device__ void eig3f(const float K[3][3], float w[3], float V[3][3])
{
  const float p1 = K[0][1]*K[0][1] + K[0][2]*K[0][2] + K[1][2]*K[1][2];
  const float q  = (K[0][0] + K[1][1] + K[2][2]) * (1.f/3.f);
  const float p2 = (K[0][0]-q)*(K[0][0]-q) + (K[1][1]-q)*(K[1][1]-q)
                 + (K[2][2]-q)*(K[2][2]-q) + 2.f*p1;
  if (p2 < 1e-20f) {
    w[0]=w[1]=w[2]=q;
    V[0][0]=1;V[1][0]=0;V[2][0]=0; V[0][1]=0;V[1][1]=1;V[2][1]=0;
    V[0][2]=0;V[1][2]=0;V[2][2]=1;
    return;
  }
  const float p = sqrtf(p2 * (1.f/6.f));
  const float ip = 1.f / p;
  float Bm[3][3];
  for (int i = 0; i < 3; ++i)
    for (int j = 0; j < 3; ++j)
      Bm[i][j] = (K[i][j] - ((i==j) ? q : 0.f)) * ip;
  float detB = Bm[0][0]*(Bm[1][1]*Bm[2][2] - Bm[1][2]*Bm[2][1])
             - Bm[0][1]*(Bm[1][0]*Bm[2][2] - Bm[1][2]*Bm[2][0])
             + Bm[0][2]*(Bm[1][0]*Bm[2][1] - Bm[1][1]*Bm[2][0]);
  float r = fminf(1.f, fmaxf(-1.f, detB * 0.5f));
  const float phi = acosf(r) * (1.f/3.f);
  w[0] = q + 2.f*p*cosf(phi);
  w[2] = q + 2.f*p*cosf(phi + 2.0943951023931953f);
  w[1] = 3.f*q - w[0] - w[2];
  for (int kk = 0; kk < 2; ++kk) {
    const int k = (kk == 0) ? 0 : 2;
    float lam = w[k];
    float r0[3] = {K[0][0]-lam, K[0][1], K[0][2]};
    float r1[3] = {K[1][0], K[1][1]-lam, K[1][2]};
    float r2[3] = {K[2][0], K[2][1], K[2][2]-lam};
    float c01[3] = {r0[1]*r1[2]-r0[2]*r1[1], r0[2]*r1[0]-r0[0]*r1[2], r0[0]*r1[1]-r0[1]*r1[0]};
    float c12[3] = {r1[1]*r2[2]-r1[2]*r2[1], r1[2]*r2[0]-r1[0]*r2[2], r1[0]*r2[1]-r1[1]*r2[0]};
    float c20[3] = {r2[1]*r0[2]-r2[2]*r0[1], r2[2]*r0[0]-r2[0]*r0[2], r2[0]*r0[1]-r2[1]*r0[0]};
    float n01 = c01[0]*c01[0]+c01[1]*c01[1]+c01[2]*c01[2];
    float n12 = c12[0]*c12[0]+c12[1]*c12[1]+c12[2]*c12[2];
    float n20 = c20[0]*c20[0]+c20[1]*c20[1]+c20[2]*c20[2];
    float* best = c01; float nb = n01;
    if (n12 > nb) { best = c12; nb = n12; }
    if (n20 > nb) { best = c20; nb = n20; }
    float inv = 1.f / sqrtf(nb + 1e-30f);
    V[0][k]=best[0]*inv; V[1][k]=best[1]*inv; V[2][k]=best[2]*inv;
  }
  V[0][1] = V[1][2]*V[2][0] - V[2][2]*V[1][0];
  V[1][1] = V[2][2]*V[0][0] - V[0][2]*V[2][0];
  V[2][1] = V[0][2]*V[1][0] - V[1][2]*V[0][0];
  float nm = sqrtf(V[0][1]*V[0][1]+V[1][1]*V[1][1]+V[2][1]*V[2][1]) + 1e-30f;
  V[0][1] /= nm; V[1][1] /= nm; V[2][1] /= nm;
}

// Kabsch (fp32): R = V'U^T with last V column flipped if det<0.
__device__ void kabsch_Rf(const float H[3][3], float R[3][3])
{
  float K[3][3];
  for (int i = 0; i < 3; ++i)
    for (int j = 0; j < 3; ++j) {
      float s = 0.f;
      for (int k = 0; k < 3; ++k) s += H[k][i] * H[k][j];
      K[i][j] = s;
    }
  float w[3], V[3][3];
  eig3f(K, w, V);
  float U[3][3];
  for (int k = 0; k < 3; ++k) {
    float u0 = H[0][0]*V[0][k] + H[0][1]*V[1][k] + H[0][2]*V[2][k];
    float u1 = H[1][0]*V[0][k] + H[1][1]*V[1][k] + H[1][2]*V[2][k];
    float u2 = H[2][0]*V[0][k] + H[2][1]*V[1][k] + H[2][2]*V[2][k];
    float n = sqrtf(u0*u0 + u1*u1 + u2*u2);
    if (n > 1e-18f) { u0 /= n; u1 /= n; u2 /= n; }
    else if (k == 2) {
      u0 = U[1][0]*U[2][1] - U[2][0]*U[1][1];
      u1 = U[2][0]*U[0][1] - U[0][0]*U[2][1];
      u2 = U[0][0]*U[1][1] - U[1][0]*U[0][1];
      float n2 = sqrtf(u0*u0 + u1*u1 + u2*u2) + 1e-30f;
      u0 /= n2; u1 /= n2; u2 /= n2;
    } else {
      u0 = (k == 0) ? 1.f : 0.f; u1 = (k == 1) ? 1.f : 0.f; u2 = 0.f;
    }
    U[0][k] = u0; U[1][k] = u1; U[2][k] = u2;
  }
  float R0[3][3];
  for (int i = 0; i < 3; ++i)
    for (int j = 0; j < 3; ++j)
      R0[i][j] = V[i][0]*U[j][0] + V[i][1]*U[j][1] + V[i][2]*U[j][2];
  float det = R0[0][0]*(R0[1][1]*R0[2][2] - R0[1][2]*R0[2][1])
            - R0[0][1]*(R0[1][0]*R0[2][2] - R0[1][2]*R0[2][0])
            + R0[0][2]*(R0[1][0]*R0[2][1] - R0[1][1]*R0[2][0]);
  if (det < 0.f)
    for (int i = 0; i < 3; ++i)
      for (int j = 0; j < 3; ++j)
        R0[i][j] -= 2.f * V[i][2] * U[j][2];
  for (int i = 0; i < 3; ++i)
    for (int j = 0; j < 3; ++j)
      R[i][j] = R0[i][j];
}

// Generation-flag grid barrier with s_sleep backoff (proven best).
__device__ inline void flag_barrier(int* flags, int blk, int gen,
                                    int tid, int wav, int lane)
{
  __syncthreads();
  if (tid == 0) {
    __threadfence();          // release partials at agent scope
    atom_sti(&flags[blk], gen);
  }
  if (wav == 0) {
    const int base = lane * 4;
    u32 spins = 0;
    bool ok = false;
    while (!ok && spins < SPINCAP) {
      int f0 = atom_ldi(&flags[base + 0]);
      int f1 = atom_ldi(&flags[base + 1]);
      int f2_ = atom_ldi(&flags[base + 2]);
      int f3 = atom_ldi(&flags[base + 3]);
      ok = __all((f0 >= gen) && (f1 >= gen) && (f2_ >= gen) && (f3 >= gen));
      if (!ok) __builtin_amdgcn_s_sleep(2); // ~128 cyc backoff
      ++spins;
    }
  }
  __syncthreads();
  __threadfence();            // acquire everyone's partials
}

// Persistent kernel: Bp staged into LDS ONCE; all 20 iterations + final
// best-fit. block b owns src points b*32..b*32+31 (wave w: 8, in registers).
// Every block redundantly reduces+solves (deterministic => identical T/done).
__global__ __launch_bounds__(NT, 1)
void icp_all(const float* __restrict__ A, const float* __restrict__ B,
             char* __restrict__ ws, float* __restrict__ out)
{
  double* partials = (double*)(ws + WS_PART); // [2][16][NB]
  int*    flags    = (int*)(ws + WS_FLAGS);

  __shared__ __align__(16) float4 bp_lds[NPTS];   // 128 KB, persistent
  __shared__ __align__(16) double red1[32 * 16];  // per-src rows
  __shared__ double red2[4 * 16];                 // wave sums / S[k]
  __shared__ float  Tl[12];
  __shared__ int    dl;

  const int tid  = threadIdx.x;
  const int blk  = blockIdx.x;
  const int wav  = tid >> 6;
  const int lane = tid & 63;
  const int qbase = blk * 32 + wav * SRCW;

  // ---- stage Bp once (B is constant across all iterations) ----
  for (int i = tid; i < NPTS; i += NT) {
    float bx = B[3*i], by = B[3*i+1], bz = B[3*i+2];
    bp_lds[i] = make_float4(2.f*bx, 2.f*by, 2.f*bz, bx*bx + by*by + bz*bz);
  }

  float ax[8], ay[8], az[8], sx[8], sy[8], sz[8];
  #pragma unroll
  for (int i = 0; i < 8; ++i) { // broadcast loads: all lanes hold all 8 src
    int p = qbase + i;
    ax[i] = A[3*p]; ay[i] = A[3*p+1]; az[i] = A[3*p+2];
    sx[i] = ax[i];  sy[i] = ay[i];    sz[i] = az[i];
  }
  __syncthreads(); // bp_lds ready

  double prev_err = 0.0; // tid0-meaningful; identical on every block
  int it = 0;
  for (; it < MAXIT; ++it) {
    const int par = it & 1;
    // ---- 1-NN sweep: 8-dst groups, packed math (2 inst/pair), deferred idx.
    f2 nsx2[4], nsy2[4], nsz2[4];
    #pragma unroll
    for (int k = 0; k < 4; ++k) {
      f2 vx = { -sx[2*k], -sx[2*k+1] };
      f2 vy = { -sy[2*k], -sy[2*k+1] };
      f2 vz = { -sz[2*k], -sz[2*k+1] };
      nsx2[k] = vx; nsy2[k] = vy; nsz2[k] = vz;
    }

    float emin[8]; int gmin[8];
    #pragma unroll
    for (int i = 0; i < 8; ++i) { emin[i] = 3.4e38f; gmin[i] = 0; }

    float4 dd[8];
    #pragma unroll
    for (int m = 0; m < 8; ++m) dd[m] = bp_lds[m * 64 + lane];

    #pragma unroll 2
    for (int g = 0; g < NG8 - 1; ++g) {
      f2 run[4];
      #pragma unroll
      for (int m = 0; m < 8; ++m) {
        f2 dx2 = { dd[m].x, dd[m].x };
        f2 dy2 = { dd[m].y, dd[m].y };
        f2 dz2 = { dd[m].z, dd[m].z };
        f2 dw2 = { dd[m].w, dd[m].w };
        #pragma unroll
        for (int k = 0; k < 4; ++k) {
          // e = |b|^2 - 2 s.b ; argmin_j e == argmin_j d2 (d2 = e + |s|^2)
          f2 e2 = __builtin_elementwise_fma(nsx2[k], dx2,
                   __builtin_elementwise_fma(nsy2[k], dy2,
                    __builtin_elementwise_fma(nsz2[k], dz2, dw2)));
          run[k] = (m == 0) ? e2 : __builtin_elementwise_min(run[k], e2);
        }
        dd[m] = bp_lds[(g + 1) * 512 + m * 64 + lane]; // refill after last use
      }
      #pragma unroll
      for (int k = 0; k < 4; ++k) {
        if (run[k].x < emin[2*k])   gmin[2*k]   = g;
        emin[2*k]   = fminf(emin[2*k],   run[k].x);
        if (run[k].y < emin[2*k+1]) gmin[2*k+1] = g;
        emin[2*k+1] = fminf(emin[2*k+1], run[k].y);
      }
    }
    { // epilogue group g = NG8-1, no refill
      const int g = NG8 - 1;
      f2 run[4];
      #pragma unroll
      for (int m = 0; m < 8; ++m) {
        f2 dx2 = { dd[m].x, dd[m].x };
        f2 dy2 = { dd[m].y, dd[m].y };
        f2 dz2 = { dd[m].z, dd[m].z };
        f2 dw2 = { dd[m].w, dd[m].w };
        #pragma unroll
        for (int k = 0; k < 4; ++k) {
          f2 e2 = __builtin_elementwise_fma(nsx2[k], dx2,
                   __builtin_elementwise_fma(nsy2[k], dy2,
                    __builtin_elementwise_fma(nsz2[k], dz2, dw2)));
          run[k] = (m == 0) ? e2 : __builtin_elementwise_min(run[k], e2);
        }
      }
      #pragma unroll
      for (int k = 0; k < 4; ++k) {
        if (run[k].x < emin[2*k])   gmin[2*k]   = g;
        emin[2*k]   = fminf(emin[2*k],   run[k].x);
        if (run[k].y < emin[2*k+1]) gmin[2*k+1] = g;
        emin[2*k+1] = fminf(emin[2*k+1], run[k].y);
      }
    }

    // wave argmin butterfly carrying (e, meta=(g<<6)|lane); strict-< on e,
    // meta tiebreak (exact fp32 e-ties across distinct points: zero-measure,
    // deterministic across blocks/runs).
    int meta[8];
    #pragma unroll
    for (int i = 0; i < 8; ++i) meta[i] = (gmin[i] << 6) | lane;
    #pragma unroll
    for (int m = 1; m < 64; m <<= 1) {
      #pragma unroll
      for (int i = 0; i < 8; ++i) {
        float eo = __shfl_xor(emin[i], m, 64);
        int   mo = __shfl_xor(meta[i], m, 64);
        if (eo < emin[i] || (eo == emin[i] && mo < meta[i])) { emin[i] = eo; meta[i] = mo; }
      }
    }

    // ---- per-src resolution + parallel red1 write (all 64 lanes) ----
    // lane handles src isrc = lane>>3, slots (lane&7)*2, +1.
    {
      const int isrc = lane >> 3;
      float em = emin[0]; int mt = meta[0];
      float sxi = sx[0], syi = sy[0], szi = sz[0];
      #pragma unroll
      for (int k = 1; k < 8; ++k) {
        const bool p = (isrc == k);
        em  = p ? emin[k] : em;   mt  = p ? meta[k] : mt;
        sxi = p ? sx[k]  : sxi;   syi = p ? sy[k]  : syi;   szi = p ? sz[k] : szi;
      }
      const int gg = mt >> 6, ll = mt & 63;
      const int j0 = gg * 512 + ll;
      int jj = j0;
      #pragma unroll
      for (int m = 7; m >= 0; --m) { // descending: last assign = FIRST member
        float4 c = bp_lds[j0 + m * 64];
        float e = fmaf(-sxi, c.x, fmaf(-syi, c.y, fmaf(-szi, c.z, c.w)));
        jj = (e == em) ? (j0 + m * 64) : jj;
      }
      float4 dmt = bp_lds[jj];
      const float bxm = 0.5f*dmt.x, bym = 0.5f*dmt.y, bzm = 0.5f*dmt.z; // exact
      const double dsx = (double)sxi, dsy = (double)syi, dsz = (double)szi;
      const double dbx = (double)bxm, dby = (double)bym, dbz = (double)bzm;
      double w0, w1;
      switch (lane & 7) {
        case 0: w0 = dsx;       w1 = dsy;       break;
        case 1: w0 = dsz;       w1 = dbx;       break;
        case 2: w0 = dby;       w1 = dbz;       break;
        case 3: w0 = dsx * dbx; w1 = dsx * dby; break;
        case 4: w0 = dsx * dbz; w1 = dsy * dbx; break;
        case 5: w0 = dsy * dby; w1 = dsy * dbz; break;
        case 6: w0 = dsz * dbx; w1 = dsz * dby; break;
        default: {
          const float s2 = sxi*sxi + syi*syi + szi*szi;
          const float d2f = em + s2;
          w0 = dsz * dbz;
          w1 = (double)sqrtf(fmaxf(d2f, 0.f) + 1e-12f);
        } break;
      }
      dbl2 wv = { w0, w1 };
      *(dbl2*)&red1[(wav * 8 + isrc) * 16 + (lane & 7) * 2] = wv;
    }

    // ---- per-wave reduction of its own 8 rows (no cross-wave dependency) ----
    {
      const int k16 = lane & 15, h = lane >> 4;
      double s = red1[(wav*8 + h)*16 + k16] + red1[(wav*8 + 4 + h)*16 + k16];
      s += __shfl_xor(s, 16, 64);
      s += __shfl_xor(s, 32, 64);
      if (lane < 16) red2[wav * 16 + k16] = s;
    }
    __syncthreads();
    if (tid < 16) { // transposed store: partials[par][k=tid][blk]
      double ssum = red2[tid] + red2[16 + tid] + red2[32 + tid] + red2[48 + tid];
      atom_st(&partials[((size_t)par * 16 + tid) * NB + blk], ssum);
    }
    flag_barrier(flags, blk, it + 1, tid, wav, lane);

    // ---- every block: reduce 256 partials, SPLIT-K: wave w owns rows 4w..4w+3
    {
      double s0, s1, s2, s3;
      #pragma unroll
      for (int j = 0; j < 4; ++j) {
        const int k = wav * 4 + j;
        const double* row = &partials[((size_t)par * 16 + k) * NB + lane * 4];
        double t0 = atom_ld(row + 0), t1 = atom_ld(row + 1);
        double t2 = atom_ld(row + 2), t3 = atom_ld(row + 3);
        double s = ((t0 + t1) + (t2 + t3));
        #pragma unroll
        for (int m = 1; m < 64; m <<= 1) s += __shfl_xor(s, m, 64);
        if (j == 0) s0 = s; else if (j == 1) s1 = s;
        else if (j == 2) s2 = s; else s3 = s;
      }
      if (lane < 4) {
        double v = (lane == 0) ? s0 : (lane == 1) ? s1 : (lane == 2) ? s2 : s3;
        red2[wav * 4 + lane] = v; // red2[k] = S[k], k owned by exactly one wave
      }
    }
    __syncthreads();
    if (tid == 0) {
      double S[16];
      for (int k = 0; k < 16; ++k) S[k] = red2[k];
      const double invN = 1.0 / NPTS;
      double cAv[3] = {S[0]*invN, S[1]*invN, S[2]*invN};
      double cBv[3] = {S[3]*invN, S[4]*invN, S[5]*invN};
      float H[3][3];
      for (int i = 0; i < 3; ++i)
        for (int j = 0; j < 3; ++j)
          H[i][j] = (float)(S[6 + i*3 + j] - (double)NPTS * cAv[i] * cBv[j]);
      double err = S[15] * invN;           // convergence stays fp64
      int conv = (fabs(prev_err - err) < TOLER) ? 1 : 0;
      prev_err = err;
      float R[3][3];
      kabsch_Rf(H, R);                     // rotation solve in fp32
      float t0 = (float)cBv[0] - (R[0][0]*(float)cAv[0] + R[0][1]*(float)cAv[1] + R[0][2]*(float)cAv[2]);
      float t1 = (float)cBv[1] - (R[1][0]*(float)cAv[0] + R[1][1]*(float)cAv[1] + R[1][2]*(float)cAv[2]);
      float t2 = (float)cBv[2] - (R[2][0]*(float)cAv[0] + R[2][1]*(float)cAv[1] + R[2][2]*(float)cAv[2]);
      Tl[0]=R[0][0]; Tl[1]=R[0][1]; Tl[2]=R[0][2];
      Tl[3]=R[1][0]; Tl[4]=R[1][1]; Tl[5]=R[1][2];
      Tl[6]=R[2][0]; Tl[7]=R[2][1]; Tl[8]=R[2][2];
      Tl[9]=t0; Tl[10]=t1; Tl[11]=t2;
      dl = conv;
    }
    __syncthreads();
    { // apply T in fp32 (ref: new_src = T @ src, before done latches)
      float r00=Tl[0],r01=Tl[1],r02=Tl[2],r10=Tl[3],r11=Tl[4],r12=Tl[5];
      float r20=Tl[6],r21=Tl[7],r22=Tl[8],t0=Tl[9],t1=Tl[10],t2=Tl[11];
      int done = dl;
      #pragma unroll
      for (int i = 0; i < 8; ++i) {
        float nx = r00*sx[i] + r01*sy[i] + r02*sz[i] + t0;
        float ny = r10*sx[i] + r11*sy[i] + r12*sz[i] + t1;
        float nz = r20*sx[i] + r21*sy[i] + r22*sz[i] + t2;
        sx[i]=nx; sy[i]=ny; sz[i]=nz;
      }
      if (done) break; // uniform decision across all blocks
    }
  }

  // ---- final best_fit_transform(A, src): H = sum a (x) s - N cA cS^T ----
  const int fpar = (it < MAXIT) ? ((it + 1) & 1) : (MAXIT & 1);
  const int fgen = (it < MAXIT) ? (it + 2) : (MAXIT + 1);
  { // parallel red1 write, same slot mapping (row op = a, col op = s, r15 = 0)
    const int isrc = lane >> 3;
    float axi = ax[0], ayi = ay[0], azi = az[0];
    float sxi = sx[0], syi = sy[0], szi = sz[0];
    #pragma unroll
    for (int k = 1; k < 8; ++k) {
      const bool p = (isrc == k);
      axi = p ? ax[k] : axi;  ayi = p ? ay[k] : ayi;  azi = p ? az[k] : azi;
      sxi = p ? sx[k] : sxi;  syi = p ? sy[k] : syi;  szi = p ? sz[k] : szi;
    }
    const double dax = (double)axi, day = (double)ayi, daz = (double)azi;
    const double dsx = (double)sxi, dsy = (double)syi, dsz = (double)szi;
    double w0, w1;
    switch (lane & 7) {
      case 0: w0 = dax;       w1 = day;       break;
      case 1: w0 = daz;       w1 = dsx;       break;
      case 2: w0 = dsy;       w1 = dsz;       break;
      case 3: w0 = dax * dsx; w1 = dax * dsy; break;
      case 4: w0 = dax * dsz; w1 = day * dsx; break;
      case 5: w0 = day * dsy; w1 = day * dsz; break;
      case 6: w0 = daz * dsx; w1 = daz * dsy; break;
      default: w0 = daz * dsz; w1 = 0.0;      break;
    }
    dbl2 wv = { w0, w1 };
    *(dbl2*)&red1[(wav * 8 + isrc) * 16 + (lane & 7) * 2] = wv;
  }
  { // per-wave reduction of own rows
    const int k16 = lane & 15, h = lane >> 4;
    double s = red1[(wav*8 + h)*16 + k16] + red1[(wav*8 + 4 + h)*16 + k16];
    s += __shfl_xor(s, 16, 64);
    s += __shfl_xor(s, 32, 64);
    if (lane < 16) red2[wav * 16 + k16] = s;
  }
  __syncthreads();
  if (tid < 16) {
    double ssum = red2[tid] + red2[16 + tid] + red2[32 + tid] + red2[48 + tid];
    atom_st(&partials[((size_t)fpar * 16 + tid) * NB + blk], ssum);
  }
  if (blk != 0) { // non-output blocks: just arrive (release) and exit
    __syncthreads();
    if (tid == 0) { __threadfence(); atom_sti(&flags[blk], fgen); }
    return;
  }
  flag_barrier(flags, blk, fgen, tid, wav, lane);

  double a2[16];
  #pragma unroll
  for (int k = 0; k < 16; ++k)
    a2[k] = atom_ld(&partials[((size_t)fpar * 16 + k) * NB + tid]);
  for (int m = 1; m < 64; m <<= 1) {
    #pragma unroll
    for (int k = 0; k < 16; ++k) a2[k] += __shfl_xor(a2[k], m, 64);
  }
  if (lane == 0)
    for (int k = 0; k < 16; ++k) red2[wav * 16 + k] = a2[k];
  __syncthreads();
  if (tid == 0) {
    double S[16];
    for (int k = 0; k < 16; ++k)
      S[k] = red2[k] + red2[16+k] + red2[32+k] + red2[48+k];
    const double invN = 1.0 / NPTS;
    double cAv[3] = {S[0]*invN, S[1]*invN, S[2]*invN};
    double cSv[3] = {S[3]*invN, S[4]*invN, S[5]*invN};
    float H[3][3];
    for (int i = 0; i < 3; ++i)
      for (int j = 0; j < 3; ++j)
        H[i][j] = (float)(S[6 + i*3 + j] - (double)NPTS * cAv[i] * cSv[j]);
    float R[3][3];
    kabsch_Rf(H, R);
    float u0 = (float)cSv[0] - (R[0][0]*(float)cAv[0] + R[0][1]*(float)cAv[1] + R[0][2]*(float)cAv[2]);
    float u1 = (float)cSv[1] - (R[1][0]*(float)cAv[0] + R[1][1]*(float)cAv[1] + R[1][2]*(float)cAv[2]);
    float u2 = (float)cSv[2] - (R[2][0]*(float)cAv[0] + R[2][1]*(float)cAv[1] + R[2][2]*(float)cAv[2]);
    out[0]=R[0][0]; out[1]=R[0][1]; out[2]=R[0][2]; out[3]=u0;
    out[4]=R[1][0]; out[5]=R[1][1]; out[6]=R[1][2]; out[7]=u1;
    out[8]=R[2][0]; out[9]=R[2][1]; out[10]=R[2][2]; out[11]=u2;
    out[12]=0.f; out[13]=0.f; out[14]=0.f; out[15]=1.f;
  }
}

extern "C" void kernel_launch(void* const* d_in, const int* in_sizes, int n_in,
                              void* d_out, int out_size, void* d_ws, size_t ws_size,
                              hipStream_t stream) {
  const float* A = (const float*)d_in[0];
  const float* B = (const float*)d_in[1];
  float* out = (float*)d_out;
  char* ws = (char*)d_ws; // needs ~67 KB

  hipLaunchKernelGGL(icp_all, dim3(NB), dim3(NT), 0, stream, A, B, ws, out);
}